// Round 1
// baseline (1178.154 us; speedup 1.0000x reference)
//
#include <hip/hip_runtime.h>
#include <hip/hip_bf16.h>

// 2-layer GCN on MI355X.
// Pipeline: count in-degrees + build ELL adjacency (1 atomic pass) ->
// dinv = rsqrt(deg+1) -> per layer: h_s = (X@W)*dinv[row] (fp32 tiled GEMM),
// then gather-aggregate: out[i] = dinv[i]*(h_s[i] + sum_{src->i} h_s[src]) + b.

#define ELL_CAP 80   // deg ~ Poisson(16); P(deg>=80) ~ 0

// ---------------- small utility kernels ----------------

__global__ void zero_cnt(int* __restrict__ cnt, int n) {
    int i = blockIdx.x * blockDim.x + threadIdx.x;
    if (i < n) cnt[i] = 0;
}

__global__ void build_ell(const int* __restrict__ src, const int* __restrict__ dst,
                          int* __restrict__ cnt, int* __restrict__ ell, int E) {
    int e = blockIdx.x * blockDim.x + threadIdx.x;
    if (e >= E) return;
    int d = dst[e];
    int pos = atomicAdd(&cnt[d], 1);
    if (pos < ELL_CAP) ell[(size_t)d * ELL_CAP + pos] = src[e];
}

__global__ void compute_dinv(const int* __restrict__ cnt, float* __restrict__ dinv, int n) {
    int i = blockIdx.x * blockDim.x + threadIdx.x;
    if (i < n) dinv[i] = rsqrtf((float)cnt[i] + 1.0f);  // +1 self-loop
}

// ---------------- GEMM: C[i][j] = dinv[i] * sum_k A[i][k]*B[k][j] ----------------
// A: [n][128], B: [128][ncols], C: [n][ncols]. Block tile 64 rows x 64 cols,
// thread microtile 4x4. As row-major padded to 132 (conflict-free b128 reads);
// Bs staged in two 64-row halves (LDS total ~50 KB -> 3 blocks/CU).

__global__ __launch_bounds__(256) void gemm_scale(
    const float* __restrict__ A, const float* __restrict__ B,
    const float* __restrict__ dinv, float* __restrict__ C,
    int n, int ncols)
{
    __shared__ float As[64][132];
    __shared__ float Bs[64][64];
    const int tid  = threadIdx.x;
    const int row0 = blockIdx.y * 64;
    const int col0 = blockIdx.x * 64;

    // stage A: 64 rows x 128 cols = 2048 float4, 8 per thread, coalesced
    #pragma unroll
    for (int i = 0; i < 8; ++i) {
        int idx = tid + i * 256;
        int r = idx >> 5, c4 = idx & 31;
        float4 v = make_float4(0.f, 0.f, 0.f, 0.f);
        int gr = row0 + r;
        if (gr < n) v = *(const float4*)(A + (size_t)gr * 128 + c4 * 4);
        *(float4*)&As[r][c4 * 4] = v;
    }

    const int tm = (tid >> 4) << 2;   // row offset 0..60
    const int tn = (tid & 15) << 2;   // col offset 0..60
    float acc[4][4] = {};

    #pragma unroll
    for (int half = 0; half < 2; ++half) {
        __syncthreads();  // As ready (half 0) / previous Bs fully consumed (half 1)
        // stage Bs: 64 rows x 64 cols = 1024 float4, 4 per thread
        #pragma unroll
        for (int i = 0; i < 4; ++i) {
            int idx = tid + i * 256;
            int r = idx >> 4, c4 = idx & 15;
            *(float4*)&Bs[r][c4 * 4] =
                *(const float4*)(B + (size_t)(half * 64 + r) * ncols + col0 + c4 * 4);
        }
        __syncthreads();

        #pragma unroll
        for (int kg = 0; kg < 16; ++kg) {
            float4 a[4], b[4];
            #pragma unroll
            for (int j = 0; j < 4; ++j)
                a[j] = *(const float4*)&As[tm + j][half * 64 + kg * 4];
            #pragma unroll
            for (int t = 0; t < 4; ++t)
                b[t] = *(const float4*)&Bs[kg * 4 + t][tn];
            #pragma unroll
            for (int j = 0; j < 4; ++j) {
                acc[j][0] += a[j].x * b[0].x + a[j].y * b[1].x + a[j].z * b[2].x + a[j].w * b[3].x;
                acc[j][1] += a[j].x * b[0].y + a[j].y * b[1].y + a[j].z * b[2].y + a[j].w * b[3].y;
                acc[j][2] += a[j].x * b[0].z + a[j].y * b[1].z + a[j].z * b[2].z + a[j].w * b[3].z;
                acc[j][3] += a[j].x * b[0].w + a[j].y * b[1].w + a[j].z * b[2].w + a[j].w * b[3].w;
            }
        }
    }

    #pragma unroll
    for (int j = 0; j < 4; ++j) {
        int gr = row0 + tm + j;
        if (gr < n) {
            float s = dinv[gr];
            float4 o = make_float4(acc[j][0] * s, acc[j][1] * s, acc[j][2] * s, acc[j][3] * s);
            *(float4*)(C + (size_t)gr * ncols + col0 + tn) = o;
        }
    }
}

// ---------------- gather-aggregate ----------------
// One wave per node. FEAT=128: lane holds float2 (64*8B=512B coalesced row read).
// FEAT=64: lane holds float. out[i] = dinv[i]*(h[i] + sum h[src]) + bias, opt relu.

template<int FEAT>
__global__ __launch_bounds__(256) void aggregate_k(
    const float* __restrict__ h, const int* __restrict__ ell,
    const int* __restrict__ cnt, const float* __restrict__ dinv,
    const float* __restrict__ bias, float* __restrict__ out,
    int n, int do_relu)
{
    int node = blockIdx.x * 4 + (threadIdx.x >> 6);
    if (node >= n) return;
    int lane = threadIdx.x & 63;
    int deg = cnt[node];
    if (deg > ELL_CAP) deg = ELL_CAP;
    const int* __restrict__ row = ell + (size_t)node * ELL_CAP;
    float d = dinv[node];

    if (FEAT == 128) {
        const float2* __restrict__ hp = (const float2*)h;   // 64 float2 per row
        float2 acc = hp[(size_t)node * 64 + lane];          // self-loop term
        int e = 0;
        for (; e + 4 <= deg; e += 4) {
            int s0 = row[e], s1 = row[e + 1], s2 = row[e + 2], s3 = row[e + 3];
            float2 v0 = hp[(size_t)s0 * 64 + lane];
            float2 v1 = hp[(size_t)s1 * 64 + lane];
            float2 v2 = hp[(size_t)s2 * 64 + lane];
            float2 v3 = hp[(size_t)s3 * 64 + lane];
            acc.x += (v0.x + v1.x) + (v2.x + v3.x);
            acc.y += (v0.y + v1.y) + (v2.y + v3.y);
        }
        for (; e < deg; ++e) {
            float2 v = hp[(size_t)row[e] * 64 + lane];
            acc.x += v.x; acc.y += v.y;
        }
        float ox = fmaf(acc.x, d, bias[lane * 2]);
        float oy = fmaf(acc.y, d, bias[lane * 2 + 1]);
        if (do_relu) { ox = fmaxf(ox, 0.f); oy = fmaxf(oy, 0.f); }
        ((float2*)out)[(size_t)node * 64 + lane] = make_float2(ox, oy);
    } else {
        float acc = h[(size_t)node * 64 + lane];
        int e = 0;
        for (; e + 4 <= deg; e += 4) {
            int s0 = row[e], s1 = row[e + 1], s2 = row[e + 2], s3 = row[e + 3];
            acc += (h[(size_t)s0 * 64 + lane] + h[(size_t)s1 * 64 + lane])
                 + (h[(size_t)s2 * 64 + lane] + h[(size_t)s3 * 64 + lane]);
        }
        for (; e < deg; ++e) acc += h[(size_t)row[e] * 64 + lane];
        float o = fmaf(acc, d, bias[lane]);
        if (do_relu) o = fmaxf(o, 0.f);
        out[(size_t)node * 64 + lane] = o;
    }
}

// ---------------- launcher ----------------

extern "C" void kernel_launch(void* const* d_in, const int* in_sizes, int n_in,
                              void* d_out, int out_size, void* d_ws, size_t ws_size,
                              hipStream_t stream)
{
    const float* x  = (const float*)d_in[0];
    const int*   ei = (const int*)d_in[1];   // [2][E], int32 (JAX demotes int64)
    const float* W1 = (const float*)d_in[2];
    const float* b1 = (const float*)d_in[3];
    const float* W2 = (const float*)d_in[4];
    const float* b2 = (const float*)d_in[5];
    float* out = (float*)d_out;

    const int N = in_sizes[0] / 128;   // 50000
    const int E = in_sizes[1] / 2;     // 800000
    const int* src = ei;
    const int* dst = ei + E;

    // workspace carve-up (256B aligned); ws is re-poisoned 0xAA each call,
    // cnt is explicitly zeroed below, everything else is write-before-read.
    char* ws = (char*)d_ws;
    size_t off = 0;
    auto alloc = [&](size_t bytes) -> void* {
        void* p = ws + off;
        off += (bytes + 255) & ~(size_t)255;
        return p;
    };
    int*   cnt  = (int*)  alloc((size_t)N * 4);
    float* dinv = (float*)alloc((size_t)N * 4);
    int*   ell  = (int*)  alloc((size_t)N * ELL_CAP * 4);
    float* h1s  = (float*)alloc((size_t)N * 128 * 4);
    float* z1   = (float*)alloc((size_t)N * 128 * 4);
    float* h2s  = (float*)alloc((size_t)N * 64 * 4);

    zero_cnt    <<<(N + 255) / 256, 256, 0, stream>>>(cnt, N);
    build_ell   <<<(E + 255) / 256, 256, 0, stream>>>(src, dst, cnt, ell, E);
    compute_dinv<<<(N + 255) / 256, 256, 0, stream>>>(cnt, dinv, N);

    // layer 1: h1s = (x @ W1) * dinv[row]; z1 = relu(dinv*(h1s self+nbrs) + b1)
    gemm_scale<<<dim3(2, (N + 63) / 64), 256, 0, stream>>>(x, W1, dinv, h1s, N, 128);
    aggregate_k<128><<<(N + 3) / 4, 256, 0, stream>>>(h1s, ell, cnt, dinv, b1, z1, N, 1);

    // layer 2: h2s = (z1 @ W2) * dinv[row]; out = dinv*(h2s self+nbrs) + b2
    gemm_scale<<<dim3(1, (N + 63) / 64), 256, 0, stream>>>(z1, W2, dinv, h2s, N, 64);
    aggregate_k<64><<<(N + 3) / 4, 256, 0, stream>>>(h2s, ell, cnt, dinv, b2, out, N, 0);
}

// Round 2
// 280.396 us; speedup vs baseline: 4.2018x; 4.2018x over previous
//
#include <hip/hip_runtime.h>
#include <hip/hip_bf16.h>

// 2-layer GCN on MI355X.
// Pipeline: count in-degrees + build ELL adjacency (1 atomic pass) ->
// dinv = rsqrt(deg+1) -> per layer: h_s = (X@W)*dinv[row] (fp32 tiled GEMM),
// then gather-aggregate: out[i] = dinv[i]*(h_s[i] + sum_{src->i} h_s[src]) + b.
//
// R1 lesson: full unroll of the kg loop caused 256-VGPR spill (2 GB scratch
// traffic, gemm = 700 us @ 3% VALUBusy). Unroll capped at 2 + launch_bounds.

#define ELL_CAP 80   // deg ~ Poisson(16); P(deg>=80) ~ 0

// ---------------- small utility kernels ----------------

__global__ void zero_cnt(int* __restrict__ cnt, int n) {
    int i = blockIdx.x * blockDim.x + threadIdx.x;
    if (i < n) cnt[i] = 0;
}

__global__ void build_ell(const int* __restrict__ src, const int* __restrict__ dst,
                          int* __restrict__ cnt, int* __restrict__ ell, int E) {
    int e = blockIdx.x * blockDim.x + threadIdx.x;
    if (e >= E) return;
    int d = dst[e];
    int pos = atomicAdd(&cnt[d], 1);
    if (pos < ELL_CAP) ell[(size_t)d * ELL_CAP + pos] = src[e];
}

__global__ void compute_dinv(const int* __restrict__ cnt, float* __restrict__ dinv, int n) {
    int i = blockIdx.x * blockDim.x + threadIdx.x;
    if (i < n) dinv[i] = rsqrtf((float)cnt[i] + 1.0f);  // +1 self-loop
}

// ---------------- GEMM: C[i][j] = dinv[i] * sum_k A[i][k]*B[k][j] ----------------
// A: [n][128], B: [128][ncols], C: [n][ncols]. Block tile 64 rows x 64 cols,
// thread microtile 4x4. As row-major padded to 132 floats (528 B = 33*16, so
// float4 reads stay 16B-aligned and conflict-free). Bs staged in two 64-row
// halves (LDS total ~50 KB -> 3 blocks/CU; launch_bounds(256,3) caps VGPR
// at ~168 to match, preventing the R1 spill).

__global__ __launch_bounds__(256, 3) void gemm_scale(
    const float* __restrict__ A, const float* __restrict__ B,
    const float* __restrict__ dinv, float* __restrict__ C,
    int n, int ncols)
{
    __shared__ float As[64][132];
    __shared__ float Bs[64][64];
    const int tid  = threadIdx.x;
    const int row0 = blockIdx.y * 64;
    const int col0 = blockIdx.x * 64;

    // stage A: 64 rows x 128 cols = 2048 float4, 8 per thread, coalesced
    #pragma unroll
    for (int i = 0; i < 8; ++i) {
        int idx = tid + i * 256;
        int r = idx >> 5, c4 = idx & 31;
        float4 v = make_float4(0.f, 0.f, 0.f, 0.f);
        int gr = row0 + r;
        if (gr < n) v = *(const float4*)(A + (size_t)gr * 128 + c4 * 4);
        *(float4*)&As[r][c4 * 4] = v;
    }

    const int tm = (tid >> 4) << 2;   // row offset 0..60
    const int tn = (tid & 15) << 2;   // col offset 0..60
    float acc[4][4] = {};

    for (int half = 0; half < 2; ++half) {
        __syncthreads();  // As ready (half 0) / previous Bs fully consumed (half 1)
        // stage Bs: 64 rows x 64 cols = 1024 float4, 4 per thread
        #pragma unroll
        for (int i = 0; i < 4; ++i) {
            int idx = tid + i * 256;
            int r = idx >> 4, c4 = idx & 15;
            *(float4*)&Bs[r][c4 * 4] =
                *(const float4*)(B + (size_t)(half * 64 + r) * ncols + col0 + c4 * 4);
        }
        __syncthreads();

        // kg unroll capped at 2: enough for ds_read_b128 merging, keeps the
        // live set ~110 VGPRs (full unroll spilled at 256 -> 2 GB scratch).
        #pragma unroll 2
        for (int kg = 0; kg < 16; ++kg) {
            float4 a[4], b[4];
            #pragma unroll
            for (int j = 0; j < 4; ++j)
                a[j] = *(const float4*)&As[tm + j][half * 64 + kg * 4];
            #pragma unroll
            for (int t = 0; t < 4; ++t)
                b[t] = *(const float4*)&Bs[kg * 4 + t][tn];
            #pragma unroll
            for (int j = 0; j < 4; ++j) {
                acc[j][0] = fmaf(a[j].x, b[0].x, fmaf(a[j].y, b[1].x, fmaf(a[j].z, b[2].x, fmaf(a[j].w, b[3].x, acc[j][0]))));
                acc[j][1] = fmaf(a[j].x, b[0].y, fmaf(a[j].y, b[1].y, fmaf(a[j].z, b[2].y, fmaf(a[j].w, b[3].y, acc[j][1]))));
                acc[j][2] = fmaf(a[j].x, b[0].z, fmaf(a[j].y, b[1].z, fmaf(a[j].z, b[2].z, fmaf(a[j].w, b[3].z, acc[j][2]))));
                acc[j][3] = fmaf(a[j].x, b[0].w, fmaf(a[j].y, b[1].w, fmaf(a[j].z, b[2].w, fmaf(a[j].w, b[3].w, acc[j][3]))));
            }
        }
    }

    #pragma unroll
    for (int j = 0; j < 4; ++j) {
        int gr = row0 + tm + j;
        if (gr < n) {
            float s = dinv[gr];
            float4 o = make_float4(acc[j][0] * s, acc[j][1] * s, acc[j][2] * s, acc[j][3] * s);
            *(float4*)(C + (size_t)gr * ncols + col0 + tn) = o;
        }
    }
}

// ---------------- gather-aggregate ----------------
// One wave per node. FEAT=128: lane holds float2 (64*8B=512B coalesced row read).
// FEAT=64: lane holds float. out[i] = dinv[i]*(h[i] + sum h[src]) + bias, opt relu.

template<int FEAT>
__global__ __launch_bounds__(256) void aggregate_k(
    const float* __restrict__ h, const int* __restrict__ ell,
    const int* __restrict__ cnt, const float* __restrict__ dinv,
    const float* __restrict__ bias, float* __restrict__ out,
    int n, int do_relu)
{
    int node = blockIdx.x * 4 + (threadIdx.x >> 6);
    if (node >= n) return;
    int lane = threadIdx.x & 63;
    int deg = cnt[node];
    if (deg > ELL_CAP) deg = ELL_CAP;
    const int* __restrict__ row = ell + (size_t)node * ELL_CAP;
    float d = dinv[node];

    if (FEAT == 128) {
        const float2* __restrict__ hp = (const float2*)h;   // 64 float2 per row
        float2 acc = hp[(size_t)node * 64 + lane];          // self-loop term
        int e = 0;
        for (; e + 4 <= deg; e += 4) {
            int s0 = row[e], s1 = row[e + 1], s2 = row[e + 2], s3 = row[e + 3];
            float2 v0 = hp[(size_t)s0 * 64 + lane];
            float2 v1 = hp[(size_t)s1 * 64 + lane];
            float2 v2 = hp[(size_t)s2 * 64 + lane];
            float2 v3 = hp[(size_t)s3 * 64 + lane];
            acc.x += (v0.x + v1.x) + (v2.x + v3.x);
            acc.y += (v0.y + v1.y) + (v2.y + v3.y);
        }
        for (; e < deg; ++e) {
            float2 v = hp[(size_t)row[e] * 64 + lane];
            acc.x += v.x; acc.y += v.y;
        }
        float ox = fmaf(acc.x, d, bias[lane * 2]);
        float oy = fmaf(acc.y, d, bias[lane * 2 + 1]);
        if (do_relu) { ox = fmaxf(ox, 0.f); oy = fmaxf(oy, 0.f); }
        ((float2*)out)[(size_t)node * 64 + lane] = make_float2(ox, oy);
    } else {
        float acc = h[(size_t)node * 64 + lane];
        int e = 0;
        for (; e + 4 <= deg; e += 4) {
            int s0 = row[e], s1 = row[e + 1], s2 = row[e + 2], s3 = row[e + 3];
            acc += (h[(size_t)s0 * 64 + lane] + h[(size_t)s1 * 64 + lane])
                 + (h[(size_t)s2 * 64 + lane] + h[(size_t)s3 * 64 + lane]);
        }
        for (; e < deg; ++e) acc += h[(size_t)row[e] * 64 + lane];
        float o = fmaf(acc, d, bias[lane]);
        if (do_relu) o = fmaxf(o, 0.f);
        out[(size_t)node * 64 + lane] = o;
    }
}

// ---------------- launcher ----------------

extern "C" void kernel_launch(void* const* d_in, const int* in_sizes, int n_in,
                              void* d_out, int out_size, void* d_ws, size_t ws_size,
                              hipStream_t stream)
{
    const float* x  = (const float*)d_in[0];
    const int*   ei = (const int*)d_in[1];   // [2][E], int32 (JAX demotes int64)
    const float* W1 = (const float*)d_in[2];
    const float* b1 = (const float*)d_in[3];
    const float* W2 = (const float*)d_in[4];
    const float* b2 = (const float*)d_in[5];
    float* out = (float*)d_out;

    const int N = in_sizes[0] / 128;   // 50000
    const int E = in_sizes[1] / 2;     // 800000
    const int* src = ei;
    const int* dst = ei + E;

    // workspace carve-up (256B aligned); ws is re-poisoned 0xAA each call,
    // cnt is explicitly zeroed below, everything else is write-before-read.
    char* ws = (char*)d_ws;
    size_t off = 0;
    auto alloc = [&](size_t bytes) -> void* {
        void* p = ws + off;
        off += (bytes + 255) & ~(size_t)255;
        return p;
    };
    int*   cnt  = (int*)  alloc((size_t)N * 4);
    float* dinv = (float*)alloc((size_t)N * 4);
    int*   ell  = (int*)  alloc((size_t)N * ELL_CAP * 4);
    float* h1s  = (float*)alloc((size_t)N * 128 * 4);
    float* z1   = (float*)alloc((size_t)N * 128 * 4);
    float* h2s  = (float*)alloc((size_t)N * 64 * 4);

    zero_cnt    <<<(N + 255) / 256, 256, 0, stream>>>(cnt, N);
    build_ell   <<<(E + 255) / 256, 256, 0, stream>>>(src, dst, cnt, ell, E);
    compute_dinv<<<(N + 255) / 256, 256, 0, stream>>>(cnt, dinv, N);

    // layer 1: h1s = (x @ W1) * dinv[row]; z1 = relu(dinv*(h1s self+nbrs) + b1)
    gemm_scale<<<dim3(2, (N + 63) / 64), 256, 0, stream>>>(x, W1, dinv, h1s, N, 128);
    aggregate_k<128><<<(N + 3) / 4, 256, 0, stream>>>(h1s, ell, cnt, dinv, b1, z1, N, 1);

    // layer 2: h2s = (z1 @ W2) * dinv[row]; out = dinv*(h2s self+nbrs) + b2
    gemm_scale<<<dim3(1, (N + 63) / 64), 256, 0, stream>>>(z1, W2, dinv, h2s, N, 64);
    aggregate_k<64><<<(N + 3) / 4, 256, 0, stream>>>(h2s, ell, cnt, dinv, b2, out, N, 0);
}

// Round 3
// 242.197 us; speedup vs baseline: 4.8644x; 1.1577x over previous
//
#include <hip/hip_runtime.h>
#include <hip/hip_bf16.h>

// 2-layer GCN on MI355X.
// R2 state: fp32 GEMM ~75us combined, aggregates ~95us, total 280us.
// R3: GEMMs -> bf16 MFMA (mfma_f32_16x16x32_bf16). x/W converted to bf16 once;
// aggregate1 writes z1 directly as bf16 (gemm2's A operand). Gather sources
// (h1s/h2s) stay fp32 to preserve accuracy margin (threshold 1.008e-2).

#define ELL_CAP 64   // deg ~ Poisson(16); P(deg>=64) ~ 1e-18

typedef __attribute__((ext_vector_type(8))) short short8;   // 8 bf16 (4 VGPRs)
typedef __attribute__((ext_vector_type(4))) float f32x4;

static __device__ __forceinline__ unsigned short f2bf(float f) {
    unsigned int u = __float_as_uint(f);
    u = (u + 0x7fff + ((u >> 16) & 1)) >> 16;   // round-to-nearest-even
    return (unsigned short)u;
}

// ---------------- small utility kernels ----------------

__global__ void zero_cnt(int* __restrict__ cnt, int n) {
    int i = blockIdx.x * blockDim.x + threadIdx.x;
    if (i < n) cnt[i] = 0;
}

__global__ void build_ell(const int* __restrict__ src, const int* __restrict__ dst,
                          int* __restrict__ cnt, int* __restrict__ ell, int E) {
    int e = blockIdx.x * blockDim.x + threadIdx.x;
    if (e >= E) return;
    int d = dst[e];
    int pos = atomicAdd(&cnt[d], 1);
    if (pos < ELL_CAP) ell[(size_t)d * ELL_CAP + pos] = src[e];
}

__global__ void compute_dinv(const int* __restrict__ cnt, float* __restrict__ dinv, int n) {
    int i = blockIdx.x * blockDim.x + threadIdx.x;
    if (i < n) dinv[i] = rsqrtf((float)cnt[i] + 1.0f);  // +1 self-loop
}

__global__ void f32_to_bf16_vec(const float* __restrict__ in, unsigned short* __restrict__ out, int n4) {
    int i = blockIdx.x * blockDim.x + threadIdx.x;
    if (i >= n4) return;
    float4 v = ((const float4*)in)[i];
    ushort4 o;
    o.x = f2bf(v.x); o.y = f2bf(v.y); o.z = f2bf(v.z); o.w = f2bf(v.w);
    ((ushort4*)out)[i] = o;
}

// wt[n][k] = bf16(w[k][n]); w is [128][ncols], wt is [ncols][128]
__global__ void transpose_w_bf16(const float* __restrict__ w, short* __restrict__ wt, int ncols) {
    int i = blockIdx.x * blockDim.x + threadIdx.x;
    if (i >= 128 * ncols) return;
    int k = i / ncols, nn = i % ncols;
    wt[nn * 128 + k] = (short)f2bf(w[i]);
}

// ---------------- MFMA GEMM: C[i][j] = dinv[i] * sum_k A[i][k]*W[k][j] --------
// A: [n][128] bf16, Bt: [NC][128] bf16 (W transposed), C: [n][NC] fp32.
// Block = 64 rows x NC cols, 4 waves, wave = 16-row strip.
// Bt staged in LDS padded to stride 136 shorts (272 B): b128 reads land
// 2 lanes/bank (free) instead of 16-way conflicts at stride 128.
// n must be a multiple of 16 (50000 = 16*3125) so waves are uniformly in/out.

template<int NC>
__global__ __launch_bounds__(256) void gemm_mfma(
    const short* __restrict__ A, const short* __restrict__ Bt,
    const float* __restrict__ dinv, float* __restrict__ C, int n)
{
    __shared__ short Bs[NC][136];
    const int tid = threadIdx.x;

    #pragma unroll
    for (int i = 0; i < NC / 16; ++i) {      // NC*128 shorts, 16B per thread/iter
        int idx = tid + i * 256;
        int nrow = idx >> 4;
        int kcol = (idx & 15) * 8;
        *(short8*)&Bs[nrow][kcol] = *(const short8*)(Bt + nrow * 128 + kcol);
    }
    __syncthreads();

    const int wave = tid >> 6, lane = tid & 63;
    const int row0 = blockIdx.x * 64 + wave * 16;
    if (row0 >= n) return;
    const int quad = lane >> 4, l16 = lane & 15;

    // A fragments: lane holds A[row0+l16][kk*32 + quad*8 .. +7]
    short8 af[4];
    const short* arow = A + (size_t)(row0 + l16) * 128 + quad * 8;
    #pragma unroll
    for (int kk = 0; kk < 4; ++kk)
        af[kk] = *(const short8*)(arow + kk * 32);

    // dinv for this lane's 4 output rows (row = quad*4 + r)
    float dv[4];
    #pragma unroll
    for (int r = 0; r < 4; ++r) dv[r] = dinv[row0 + quad * 4 + r];

    #pragma unroll
    for (int t = 0; t < NC / 16; ++t) {
        f32x4 acc = {0.f, 0.f, 0.f, 0.f};
        #pragma unroll
        for (int kk = 0; kk < 4; ++kk) {
            short8 bfr = *(const short8*)&Bs[t * 16 + l16][kk * 32 + quad * 8];
            acc = __builtin_amdgcn_mfma_f32_16x16x32_bf16(af[kk], bfr, acc, 0, 0, 0);
        }
        #pragma unroll
        for (int r = 0; r < 4; ++r) {
            int gr = row0 + quad * 4 + r;
            C[(size_t)gr * NC + t * 16 + l16] = acc[r] * dv[r];
        }
    }
}

// ---------------- gather-aggregate ----------------
// One wave per node. Layer 1 (FEAT=128): lane holds float2, out = bf16 z1
// (packed uint) with relu. Layer 2 (FEAT=64): lane holds float, fp32 out.

__global__ __launch_bounds__(256) void aggregate_l1(
    const float* __restrict__ h, const int* __restrict__ ell,
    const int* __restrict__ cnt, const float* __restrict__ dinv,
    const float* __restrict__ bias, unsigned int* __restrict__ z1b, int n)
{
    int node = blockIdx.x * 4 + (threadIdx.x >> 6);
    if (node >= n) return;
    int lane = threadIdx.x & 63;
    int deg = cnt[node];
    if (deg > ELL_CAP) deg = ELL_CAP;
    const int* __restrict__ row = ell + (size_t)node * ELL_CAP;
    float d = dinv[node];

    const float2* __restrict__ hp = (const float2*)h;   // 64 float2 per row
    float2 acc = hp[(size_t)node * 64 + lane];          // self-loop term
    int e = 0;
    for (; e + 4 <= deg; e += 4) {
        int s0 = row[e], s1 = row[e + 1], s2 = row[e + 2], s3 = row[e + 3];
        float2 v0 = hp[(size_t)s0 * 64 + lane];
        float2 v1 = hp[(size_t)s1 * 64 + lane];
        float2 v2 = hp[(size_t)s2 * 64 + lane];
        float2 v3 = hp[(size_t)s3 * 64 + lane];
        acc.x += (v0.x + v1.x) + (v2.x + v3.x);
        acc.y += (v0.y + v1.y) + (v2.y + v3.y);
    }
    for (; e < deg; ++e) {
        float2 v = hp[(size_t)row[e] * 64 + lane];
        acc.x += v.x; acc.y += v.y;
    }
    float ox = fmaxf(fmaf(acc.x, d, bias[lane * 2]), 0.f);
    float oy = fmaxf(fmaf(acc.y, d, bias[lane * 2 + 1]), 0.f);
    z1b[(size_t)node * 64 + lane] =
        (unsigned int)f2bf(ox) | ((unsigned int)f2bf(oy) << 16);
}

__global__ __launch_bounds__(256) void aggregate_l2(
    const float* __restrict__ h, const int* __restrict__ ell,
    const int* __restrict__ cnt, const float* __restrict__ dinv,
    const float* __restrict__ bias, float* __restrict__ out, int n)
{
    int node = blockIdx.x * 4 + (threadIdx.x >> 6);
    if (node >= n) return;
    int lane = threadIdx.x & 63;
    int deg = cnt[node];
    if (deg > ELL_CAP) deg = ELL_CAP;
    const int* __restrict__ row = ell + (size_t)node * ELL_CAP;
    float d = dinv[node];

    float acc = h[(size_t)node * 64 + lane];
    int e = 0;
    for (; e + 4 <= deg; e += 4) {
        int s0 = row[e], s1 = row[e + 1], s2 = row[e + 2], s3 = row[e + 3];
        acc += (h[(size_t)s0 * 64 + lane] + h[(size_t)s1 * 64 + lane])
             + (h[(size_t)s2 * 64 + lane] + h[(size_t)s3 * 64 + lane]);
    }
    for (; e < deg; ++e) acc += h[(size_t)row[e] * 64 + lane];
    out[(size_t)node * 64 + lane] = fmaf(acc, d, bias[lane]);
}

// ---------------- launcher ----------------

extern "C" void kernel_launch(void* const* d_in, const int* in_sizes, int n_in,
                              void* d_out, int out_size, void* d_ws, size_t ws_size,
                              hipStream_t stream)
{
    const float* x  = (const float*)d_in[0];
    const int*   ei = (const int*)d_in[1];   // [2][E] int32
    const float* W1 = (const float*)d_in[2];
    const float* b1 = (const float*)d_in[3];
    const float* W2 = (const float*)d_in[4];
    const float* b2 = (const float*)d_in[5];
    float* out = (float*)d_out;

    const int N = in_sizes[0] / 128;   // 50000
    const int E = in_sizes[1] / 2;     // 800000
    const int* src = ei;
    const int* dst = ei + E;

    char* ws = (char*)d_ws;
    size_t off = 0;
    auto alloc = [&](size_t bytes) -> void* {
        void* p = ws + off;
        off += (bytes + 255) & ~(size_t)255;
        return p;
    };
    int*            cnt  = (int*)           alloc((size_t)N * 4);
    float*          dinv = (float*)         alloc((size_t)N * 4);
    int*            ell  = (int*)           alloc((size_t)N * ELL_CAP * 4);
    unsigned short* xb   = (unsigned short*)alloc((size_t)N * 128 * 2);
    short*          w1t  = (short*)         alloc((size_t)128 * 128 * 2);
    short*          w2t  = (short*)         alloc((size_t)64 * 128 * 2);
    float*          h1s  = (float*)         alloc((size_t)N * 128 * 4);
    unsigned int*   z1b  = (unsigned int*)  alloc((size_t)N * 64 * 4);  // bf16x2 packed
    float*          h2s  = (float*)         alloc((size_t)N * 64 * 4);

    zero_cnt    <<<(N + 255) / 256, 256, 0, stream>>>(cnt, N);
    build_ell   <<<(E + 255) / 256, 256, 0, stream>>>(src, dst, cnt, ell, E);
    compute_dinv<<<(N + 255) / 256, 256, 0, stream>>>(cnt, dinv, N);

    f32_to_bf16_vec<<<(N * 128 / 4 + 255) / 256, 256, 0, stream>>>(x, xb, N * 128 / 4);
    transpose_w_bf16<<<(128 * 128 + 255) / 256, 256, 0, stream>>>(W1, w1t, 128);
    transpose_w_bf16<<<(128 * 64 + 255) / 256, 256, 0, stream>>>(W2, w2t, 64);

    // layer 1
    gemm_mfma<128><<<(N + 63) / 64, 256, 0, stream>>>((const short*)xb, w1t, dinv, h1s, N);
    aggregate_l1<<<(N + 3) / 4, 256, 0, stream>>>(h1s, ell, cnt, dinv, b1, z1b, N);

    // layer 2
    gemm_mfma<64><<<(N + 63) / 64, 256, 0, stream>>>((const short*)z1b, w2t, dinv, h2s, N);
    aggregate_l2<<<(N + 3) / 4, 256, 0, stream>>>(h2s, ell, cnt, dinv, b2, out, N);
}

// Round 4
// 210.256 us; speedup vs baseline: 5.6034x; 1.1519x over previous
//
#include <hip/hip_runtime.h>
#include <hip/hip_bf16.h>

// 2-layer GCN on MI355X.
// R3 state: MFMA gemms off the critical path; aggregate gathers dominate
// (agg1 57.5us @ 435 MB logical, 186 MB HBM). R4: h1/h2 stored as bf16
// (packed uint) -> gather bytes halve at every cache level. agg2 runs two
// nodes per wave (32 lanes x 4B = 128B coalesced rows).

#define ELL_CAP 64   // deg ~ Poisson(16); P(deg>=64) ~ 1e-18

typedef __attribute__((ext_vector_type(8))) short short8;   // 8 bf16 (4 VGPRs)
typedef __attribute__((ext_vector_type(4))) float f32x4;

static __device__ __forceinline__ unsigned short f2bf(float f) {
    unsigned int u = __float_as_uint(f);
    u = (u + 0x7fff + ((u >> 16) & 1)) >> 16;   // round-to-nearest-even
    return (unsigned short)u;
}
static __device__ __forceinline__ float2 bfunpack(unsigned int u) {
    return make_float2(__uint_as_float(u << 16),            // low short  = feat 2i
                       __uint_as_float(u & 0xffff0000u));   // high short = feat 2i+1
}

// ---------------- small utility kernels ----------------

__global__ void zero_cnt(int* __restrict__ cnt, int n) {
    int i = blockIdx.x * blockDim.x + threadIdx.x;
    if (i < n) cnt[i] = 0;
}

__global__ void build_ell(const int* __restrict__ src, const int* __restrict__ dst,
                          int* __restrict__ cnt, int* __restrict__ ell, int E) {
    int e = blockIdx.x * blockDim.x + threadIdx.x;
    if (e >= E) return;
    int d = dst[e];
    int pos = atomicAdd(&cnt[d], 1);
    if (pos < ELL_CAP) ell[(size_t)d * ELL_CAP + pos] = src[e];
}

__global__ void compute_dinv(const int* __restrict__ cnt, float* __restrict__ dinv, int n) {
    int i = blockIdx.x * blockDim.x + threadIdx.x;
    if (i < n) dinv[i] = rsqrtf((float)cnt[i] + 1.0f);  // +1 self-loop
}

__global__ void f32_to_bf16_vec(const float* __restrict__ in, unsigned short* __restrict__ out, int n4) {
    int i = blockIdx.x * blockDim.x + threadIdx.x;
    if (i >= n4) return;
    float4 v = ((const float4*)in)[i];
    ushort4 o;
    o.x = f2bf(v.x); o.y = f2bf(v.y); o.z = f2bf(v.z); o.w = f2bf(v.w);
    ((ushort4*)out)[i] = o;
}

// wt[n][k] = bf16(w[k][n]); w is [128][ncols], wt is [ncols][128]
__global__ void transpose_w_bf16(const float* __restrict__ w, short* __restrict__ wt, int ncols) {
    int i = blockIdx.x * blockDim.x + threadIdx.x;
    if (i >= 128 * ncols) return;
    int k = i / ncols, nn = i % ncols;
    wt[nn * 128 + k] = (short)f2bf(w[i]);
}

// ---------------- MFMA GEMM: Cb[i][j] = bf16(dinv[i] * sum_k A[i][k]*W[k][j]) --
// A: [n][128] bf16, Bt: [NC][128] bf16 (W transposed), Cb: [n][NC] bf16.
// Block = 64 rows x NC cols, 4 waves, wave = 16-row strip. Bs padded to 136
// shorts (b128 reads 2 lanes/bank = free). n % 16 == 0 (50000 = 16*3125).

template<int NC>
__global__ __launch_bounds__(256) void gemm_mfma(
    const short* __restrict__ A, const short* __restrict__ Bt,
    const float* __restrict__ dinv, unsigned short* __restrict__ Cb, int n)
{
    __shared__ short Bs[NC][136];
    const int tid = threadIdx.x;

    #pragma unroll
    for (int i = 0; i < NC / 16; ++i) {      // NC*128 shorts, 16B per thread/iter
        int idx = tid + i * 256;
        int nrow = idx >> 4;
        int kcol = (idx & 15) * 8;
        *(short8*)&Bs[nrow][kcol] = *(const short8*)(Bt + nrow * 128 + kcol);
    }
    __syncthreads();

    const int wave = tid >> 6, lane = tid & 63;
    const int row0 = blockIdx.x * 64 + wave * 16;
    if (row0 >= n) return;
    const int quad = lane >> 4, l16 = lane & 15;

    // A fragments: lane holds A[row0+l16][kk*32 + quad*8 .. +7]
    short8 af[4];
    const short* arow = A + (size_t)(row0 + l16) * 128 + quad * 8;
    #pragma unroll
    for (int kk = 0; kk < 4; ++kk)
        af[kk] = *(const short8*)(arow + kk * 32);

    // dinv for this lane's 4 output rows (row = quad*4 + r)
    float dv[4];
    #pragma unroll
    for (int r = 0; r < 4; ++r) dv[r] = dinv[row0 + quad * 4 + r];

    #pragma unroll
    for (int t = 0; t < NC / 16; ++t) {
        f32x4 acc = {0.f, 0.f, 0.f, 0.f};
        #pragma unroll
        for (int kk = 0; kk < 4; ++kk) {
            short8 bfr = *(const short8*)&Bs[t * 16 + l16][kk * 32 + quad * 8];
            acc = __builtin_amdgcn_mfma_f32_16x16x32_bf16(af[kk], bfr, acc, 0, 0, 0);
        }
        #pragma unroll
        for (int r = 0; r < 4; ++r) {
            int gr = row0 + quad * 4 + r;
            Cb[(size_t)gr * NC + t * 16 + l16] = f2bf(acc[r] * dv[r]);
        }
    }
}

// ---------------- gather-aggregate ----------------
// Layer 1: one wave per node, lane loads uint (2 bf16 feats of 128), fp32
// accumulate, writes z1 packed bf16 (gemm2's A operand) with relu.

__global__ __launch_bounds__(256) void aggregate_l1(
    const unsigned int* __restrict__ hp, const int* __restrict__ ell,
    const int* __restrict__ cnt, const float* __restrict__ dinv,
    const float* __restrict__ bias, unsigned int* __restrict__ z1b, int n)
{
    int node = blockIdx.x * 4 + (threadIdx.x >> 6);
    if (node >= n) return;
    int lane = threadIdx.x & 63;
    int deg = cnt[node];
    if (deg > ELL_CAP) deg = ELL_CAP;
    const int* __restrict__ row = ell + (size_t)node * ELL_CAP;
    float d = dinv[node];

    float2 acc = bfunpack(hp[(size_t)node * 64 + lane]);   // self-loop term
    int e = 0;
    for (; e + 4 <= deg; e += 4) {
        int s0 = row[e], s1 = row[e + 1], s2 = row[e + 2], s3 = row[e + 3];
        float2 v0 = bfunpack(hp[(size_t)s0 * 64 + lane]);
        float2 v1 = bfunpack(hp[(size_t)s1 * 64 + lane]);
        float2 v2 = bfunpack(hp[(size_t)s2 * 64 + lane]);
        float2 v3 = bfunpack(hp[(size_t)s3 * 64 + lane]);
        acc.x += (v0.x + v1.x) + (v2.x + v3.x);
        acc.y += (v0.y + v1.y) + (v2.y + v3.y);
    }
    for (; e < deg; ++e) {
        float2 v = bfunpack(hp[(size_t)row[e] * 64 + lane]);
        acc.x += v.x; acc.y += v.y;
    }
    float ox = fmaxf(fmaf(acc.x, d, bias[lane * 2]), 0.f);
    float oy = fmaxf(fmaf(acc.y, d, bias[lane * 2 + 1]), 0.f);
    z1b[(size_t)node * 64 + lane] =
        (unsigned int)f2bf(ox) | ((unsigned int)f2bf(oy) << 16);
}

// Layer 2: two nodes per wave (half-wave = 32 lanes x uint = 128B row),
// fp32 output straight to d_out.

__global__ __launch_bounds__(256) void aggregate_l2(
    const unsigned int* __restrict__ hp, const int* __restrict__ ell,
    const int* __restrict__ cnt, const float* __restrict__ dinv,
    const float* __restrict__ bias, float* __restrict__ out, int n)
{
    int lane = threadIdx.x & 63;
    int half = lane >> 5, l32 = lane & 31;
    int node = blockIdx.x * 8 + (threadIdx.x >> 6) * 2 + half;
    if (node >= n) return;
    int deg = cnt[node];
    if (deg > ELL_CAP) deg = ELL_CAP;
    const int* __restrict__ row = ell + (size_t)node * ELL_CAP;
    float d = dinv[node];

    float2 acc = bfunpack(hp[(size_t)node * 32 + l32]);    // self-loop term
    int e = 0;
    for (; e + 4 <= deg; e += 4) {
        int s0 = row[e], s1 = row[e + 1], s2 = row[e + 2], s3 = row[e + 3];
        float2 v0 = bfunpack(hp[(size_t)s0 * 32 + l32]);
        float2 v1 = bfunpack(hp[(size_t)s1 * 32 + l32]);
        float2 v2 = bfunpack(hp[(size_t)s2 * 32 + l32]);
        float2 v3 = bfunpack(hp[(size_t)s3 * 32 + l32]);
        acc.x += (v0.x + v1.x) + (v2.x + v3.x);
        acc.y += (v0.y + v1.y) + (v2.y + v3.y);
    }
    for (; e < deg; ++e) {
        float2 v = bfunpack(hp[(size_t)row[e] * 32 + l32]);
        acc.x += v.x; acc.y += v.y;
    }
    float2 o;
    o.x = fmaf(acc.x, d, bias[l32 * 2]);
    o.y = fmaf(acc.y, d, bias[l32 * 2 + 1]);
    ((float2*)out)[(size_t)node * 32 + l32] = o;
}

// ---------------- launcher ----------------

extern "C" void kernel_launch(void* const* d_in, const int* in_sizes, int n_in,
                              void* d_out, int out_size, void* d_ws, size_t ws_size,
                              hipStream_t stream)
{
    const float* x  = (const float*)d_in[0];
    const int*   ei = (const int*)d_in[1];   // [2][E] int32
    const float* W1 = (const float*)d_in[2];
    const float* b1 = (const float*)d_in[3];
    const float* W2 = (const float*)d_in[4];
    const float* b2 = (const float*)d_in[5];
    float* out = (float*)d_out;

    const int N = in_sizes[0] / 128;   // 50000
    const int E = in_sizes[1] / 2;     // 800000
    const int* src = ei;
    const int* dst = ei + E;

    char* ws = (char*)d_ws;
    size_t off = 0;
    auto alloc = [&](size_t bytes) -> void* {
        void* p = ws + off;
        off += (bytes + 255) & ~(size_t)255;
        return p;
    };
    int*            cnt  = (int*)           alloc((size_t)N * 4);
    float*          dinv = (float*)         alloc((size_t)N * 4);
    int*            ell  = (int*)           alloc((size_t)N * ELL_CAP * 4);
    unsigned short* xb   = (unsigned short*)alloc((size_t)N * 128 * 2);
    short*          w1t  = (short*)         alloc((size_t)128 * 128 * 2);
    short*          w2t  = (short*)         alloc((size_t)64 * 128 * 2);
    unsigned short* h1b  = (unsigned short*)alloc((size_t)N * 128 * 2);  // bf16
    unsigned int*   z1b  = (unsigned int*)  alloc((size_t)N * 64 * 4);   // bf16x2
    unsigned short* h2b  = (unsigned short*)alloc((size_t)N * 64 * 2);   // bf16

    zero_cnt    <<<(N + 255) / 256, 256, 0, stream>>>(cnt, N);
    build_ell   <<<(E + 255) / 256, 256, 0, stream>>>(src, dst, cnt, ell, E);
    compute_dinv<<<(N + 255) / 256, 256, 0, stream>>>(cnt, dinv, N);

    f32_to_bf16_vec<<<(N * 128 / 4 + 255) / 256, 256, 0, stream>>>(x, xb, N * 128 / 4);
    transpose_w_bf16<<<(128 * 128 + 255) / 256, 256, 0, stream>>>(W1, w1t, 128);
    transpose_w_bf16<<<(128 * 64 + 255) / 256, 256, 0, stream>>>(W2, w2t, 64);

    // layer 1
    gemm_mfma<128><<<(N + 63) / 64, 256, 0, stream>>>((const short*)xb, w1t, dinv, h1b, N);
    aggregate_l1<<<(N + 3) / 4, 256, 0, stream>>>((const unsigned int*)h1b, ell, cnt, dinv, b1, z1b, N);

    // layer 2
    gemm_mfma<64><<<(N + 63) / 64, 256, 0, stream>>>((const short*)z1b, w2t, dinv, h2b, N);
    aggregate_l2<<<(N + 7) / 8, 256, 0, stream>>>((const unsigned int*)h2b, ell, cnt, dinv, b2, out, N);
}

// Round 5
// 197.271 us; speedup vs baseline: 5.9723x; 1.0658x over previous
//
#include <hip/hip_runtime.h>
#include <hip/hip_bf16.h>

// 2-layer GCN on MI355X.
// R4 state: build_ell dominates (47us) - 48 MB WRITE_SIZE = cross-XCD line
// ping-pong on scattered ELL inserts + cnt atomics.
// R5: XCD-partitioned build (block b -> dst partition b&7, matching the
// round-robin blockIdx->XCD mapping; each partition rescans the L3-resident
// edge list). Also: gemm1 converts fp32 A in-flight (kills the x->bf16 pass),
// rsqrt(cnt+1) computed inline everywhere (kills compute_dinv), weight
// transposes fused into one launch. 10 dispatches -> 7.

#define ELL_CAP 64   // deg ~ Poisson(16); P(deg>=64) ~ 1e-18
#define NPART 8      // = XCD count

typedef __attribute__((ext_vector_type(8))) short short8;   // 8 bf16 (4 VGPRs)
typedef __attribute__((ext_vector_type(4))) float f32x4;

static __device__ __forceinline__ unsigned short f2bf(float f) {
    unsigned int u = __float_as_uint(f);
    u = (u + 0x7fff + ((u >> 16) & 1)) >> 16;   // round-to-nearest-even
    return (unsigned short)u;
}
static __device__ __forceinline__ float2 bfunpack(unsigned int u) {
    return make_float2(__uint_as_float(u << 16),            // low short  = feat 2i
                       __uint_as_float(u & 0xffff0000u));   // high short = feat 2i+1
}

// ---------------- small utility kernels ----------------

__global__ void zero_cnt(int* __restrict__ cnt, int n) {
    int i = blockIdx.x * blockDim.x + threadIdx.x;
    if (i < n) cnt[i] = 0;
}

// XCD-partitioned ELL build. Block b: dst partition (b & 7), edge chunk (b >> 3).
// All atomics/writes for a node come from one XCD -> lines stay in that L2.
__global__ __launch_bounds__(256) void build_ell_part(
    const int* __restrict__ src, const int* __restrict__ dst,
    int* __restrict__ cnt, int* __restrict__ ell, int E, int partSize)
{
    const int part   = blockIdx.x & (NPART - 1);
    const int chunk  = blockIdx.x >> 3;
    const int nchunk = gridDim.x >> 3;
    const int lo = part * partSize, hi = lo + partSize;
    const int per = (E + nchunk - 1) / nchunk;
    const int e1 = min((chunk + 1) * per, E);
    for (int e = chunk * per + threadIdx.x; e < e1; e += 256) {
        int d = dst[e];
        if (d >= lo && d < hi) {
            int pos = atomicAdd(&cnt[d], 1);
            if (pos < ELL_CAP) ell[(size_t)d * ELL_CAP + pos] = src[e];
        }
    }
}

// both weight transposes in one launch: wt[n][k] = bf16(w[k][n])
__global__ void convert_weights(const float* __restrict__ W1, const float* __restrict__ W2,
                                short* __restrict__ w1t, short* __restrict__ w2t)
{
    int i = blockIdx.x * blockDim.x + threadIdx.x;
    if (i < 128 * 128) {
        int k = i >> 7, nn = i & 127;
        w1t[nn * 128 + k] = (short)f2bf(W1[i]);
    } else if (i < 128 * 128 + 128 * 64) {
        int j = i - 128 * 128;
        int k = j >> 6, nn = j & 63;
        w2t[nn * 128 + k] = (short)f2bf(W2[j]);
    }
}

// ---------------- MFMA GEMM: Cb[i][j] = bf16(dinv[i] * sum_k A[i][k]*W[k][j]) --
// A: [n][128] (fp32 if AF32, converted in-flight, else bf16),
// Bt: [NC][128] bf16 (W transposed), Cb: [n][NC] bf16.
// Block = 64 rows x NC cols, 4 waves, wave = 16-row strip. Bs padded to 136
// shorts (b128 reads 2 lanes/bank = free). n % 16 == 0 (50000 = 16*3125).
// dinv computed inline as rsqrt(cnt+1).

template<int NC, bool AF32>
__global__ __launch_bounds__(256) void gemm_mfma(
    const void* __restrict__ Av, const short* __restrict__ Bt,
    const int* __restrict__ cnt, unsigned short* __restrict__ Cb, int n)
{
    __shared__ short Bs[NC][136];
    const int tid = threadIdx.x;

    #pragma unroll
    for (int i = 0; i < NC / 16; ++i) {      // NC*128 shorts, 16B per thread/iter
        int idx = tid + i * 256;
        int nrow = idx >> 4;
        int kcol = (idx & 15) * 8;
        *(short8*)&Bs[nrow][kcol] = *(const short8*)(Bt + nrow * 128 + kcol);
    }
    __syncthreads();

    const int wave = tid >> 6, lane = tid & 63;
    const int row0 = blockIdx.x * 64 + wave * 16;
    if (row0 >= n) return;
    const int quad = lane >> 4, l16 = lane & 15;

    // A fragments: lane holds A[row0+l16][kk*32 + quad*8 .. +7]
    short8 af[4];
    if (AF32) {
        const float* arow = (const float*)Av + (size_t)(row0 + l16) * 128 + quad * 8;
        #pragma unroll
        for (int kk = 0; kk < 4; ++kk) {
            float4 u = *(const float4*)(arow + kk * 32);
            float4 v = *(const float4*)(arow + kk * 32 + 4);
            short8 f;
            f[0] = (short)f2bf(u.x); f[1] = (short)f2bf(u.y);
            f[2] = (short)f2bf(u.z); f[3] = (short)f2bf(u.w);
            f[4] = (short)f2bf(v.x); f[5] = (short)f2bf(v.y);
            f[6] = (short)f2bf(v.z); f[7] = (short)f2bf(v.w);
            af[kk] = f;
        }
    } else {
        const short* arow = (const short*)Av + (size_t)(row0 + l16) * 128 + quad * 8;
        #pragma unroll
        for (int kk = 0; kk < 4; ++kk)
            af[kk] = *(const short8*)(arow + kk * 32);
    }

    // dinv for this lane's 4 output rows (row = quad*4 + r)
    float dv[4];
    #pragma unroll
    for (int r = 0; r < 4; ++r)
        dv[r] = rsqrtf((float)cnt[row0 + quad * 4 + r] + 1.0f);

    #pragma unroll
    for (int t = 0; t < NC / 16; ++t) {
        f32x4 acc = {0.f, 0.f, 0.f, 0.f};
        #pragma unroll
        for (int kk = 0; kk < 4; ++kk) {
            short8 bfr = *(const short8*)&Bs[t * 16 + l16][kk * 32 + quad * 8];
            acc = __builtin_amdgcn_mfma_f32_16x16x32_bf16(af[kk], bfr, acc, 0, 0, 0);
        }
        #pragma unroll
        for (int r = 0; r < 4; ++r) {
            int gr = row0 + quad * 4 + r;
            Cb[(size_t)gr * NC + t * 16 + l16] = f2bf(acc[r] * dv[r]);
        }
    }
}

// ---------------- gather-aggregate ----------------
// Layer 1: one wave per node, lane loads uint (2 bf16 feats of 128), fp32
// accumulate, writes z1 packed bf16 (gemm2's A operand) with relu.

__global__ __launch_bounds__(256) void aggregate_l1(
    const unsigned int* __restrict__ hp, const int* __restrict__ ell,
    const int* __restrict__ cnt, const float* __restrict__ bias,
    unsigned int* __restrict__ z1b, int n)
{
    int node = blockIdx.x * 4 + (threadIdx.x >> 6);
    if (node >= n) return;
    int lane = threadIdx.x & 63;
    int deg = cnt[node];
    float d = rsqrtf((float)deg + 1.0f);
    if (deg > ELL_CAP) deg = ELL_CAP;
    const int* __restrict__ row = ell + (size_t)node * ELL_CAP;

    float2 acc = bfunpack(hp[(size_t)node * 64 + lane]);   // self-loop term
    int e = 0;
    for (; e + 4 <= deg; e += 4) {
        int s0 = row[e], s1 = row[e + 1], s2 = row[e + 2], s3 = row[e + 3];
        float2 v0 = bfunpack(hp[(size_t)s0 * 64 + lane]);
        float2 v1 = bfunpack(hp[(size_t)s1 * 64 + lane]);
        float2 v2 = bfunpack(hp[(size_t)s2 * 64 + lane]);
        float2 v3 = bfunpack(hp[(size_t)s3 * 64 + lane]);
        acc.x += (v0.x + v1.x) + (v2.x + v3.x);
        acc.y += (v0.y + v1.y) + (v2.y + v3.y);
    }
    for (; e < deg; ++e) {
        float2 v = bfunpack(hp[(size_t)row[e] * 64 + lane]);
        acc.x += v.x; acc.y += v.y;
    }
    float ox = fmaxf(fmaf(acc.x, d, bias[lane * 2]), 0.f);
    float oy = fmaxf(fmaf(acc.y, d, bias[lane * 2 + 1]), 0.f);
    z1b[(size_t)node * 64 + lane] =
        (unsigned int)f2bf(ox) | ((unsigned int)f2bf(oy) << 16);
}

// Layer 2: two nodes per wave (half-wave = 32 lanes x uint = 128B row),
// fp32 output straight to d_out.

__global__ __launch_bounds__(256) void aggregate_l2(
    const unsigned int* __restrict__ hp, const int* __restrict__ ell,
    const int* __restrict__ cnt, const float* __restrict__ bias,
    float* __restrict__ out, int n)
{
    int lane = threadIdx.x & 63;
    int half = lane >> 5, l32 = lane & 31;
    int node = blockIdx.x * 8 + (threadIdx.x >> 6) * 2 + half;
    if (node >= n) return;
    int deg = cnt[node];
    float d = rsqrtf((float)deg + 1.0f);
    if (deg > ELL_CAP) deg = ELL_CAP;
    const int* __restrict__ row = ell + (size_t)node * ELL_CAP;

    float2 acc = bfunpack(hp[(size_t)node * 32 + l32]);    // self-loop term
    int e = 0;
    for (; e + 4 <= deg; e += 4) {
        int s0 = row[e], s1 = row[e + 1], s2 = row[e + 2], s3 = row[e + 3];
        float2 v0 = bfunpack(hp[(size_t)s0 * 32 + l32]);
        float2 v1 = bfunpack(hp[(size_t)s1 * 32 + l32]);
        float2 v2 = bfunpack(hp[(size_t)s2 * 32 + l32]);
        float2 v3 = bfunpack(hp[(size_t)s3 * 32 + l32]);
        acc.x += (v0.x + v1.x) + (v2.x + v3.x);
        acc.y += (v0.y + v1.y) + (v2.y + v3.y);
    }
    for (; e < deg; ++e) {
        float2 v = bfunpack(hp[(size_t)row[e] * 32 + l32]);
        acc.x += v.x; acc.y += v.y;
    }
    float2 o;
    o.x = fmaf(acc.x, d, bias[l32 * 2]);
    o.y = fmaf(acc.y, d, bias[l32 * 2 + 1]);
    ((float2*)out)[(size_t)node * 32 + l32] = o;
}

// ---------------- launcher ----------------

extern "C" void kernel_launch(void* const* d_in, const int* in_sizes, int n_in,
                              void* d_out, int out_size, void* d_ws, size_t ws_size,
                              hipStream_t stream)
{
    const float* x  = (const float*)d_in[0];
    const int*   ei = (const int*)d_in[1];   // [2][E] int32
    const float* W1 = (const float*)d_in[2];
    const float* b1 = (const float*)d_in[3];
    const float* W2 = (const float*)d_in[4];
    const float* b2 = (const float*)d_in[5];
    float* out = (float*)d_out;

    const int N = in_sizes[0] / 128;   // 50000
    const int E = in_sizes[1] / 2;     // 800000
    const int* src = ei;
    const int* dst = ei + E;
    const int partSize = (N + NPART - 1) / NPART;   // 6250

    char* ws = (char*)d_ws;
    size_t off = 0;
    auto alloc = [&](size_t bytes) -> void* {
        void* p = ws + off;
        off += (bytes + 255) & ~(size_t)255;
        return p;
    };
    int*            cnt  = (int*)           alloc((size_t)N * 4);
    int*            ell  = (int*)           alloc((size_t)N * ELL_CAP * 4);
    short*          w1t  = (short*)         alloc((size_t)128 * 128 * 2);
    short*          w2t  = (short*)         alloc((size_t)64 * 128 * 2);
    unsigned short* h1b  = (unsigned short*)alloc((size_t)N * 128 * 2);  // bf16
    unsigned int*   z1b  = (unsigned int*)  alloc((size_t)N * 64 * 4);   // bf16x2
    unsigned short* h2b  = (unsigned short*)alloc((size_t)N * 64 * 2);   // bf16

    convert_weights<<<(128 * 192 + 255) / 256, 256, 0, stream>>>(W1, W2, w1t, w2t);
    zero_cnt<<<(N + 255) / 256, 256, 0, stream>>>(cnt, N);
    build_ell_part<<<128 * NPART, 256, 0, stream>>>(src, dst, cnt, ell, E, partSize);

    // layer 1 (A = fp32 x, converted in-flight)
    gemm_mfma<128, true><<<(N + 63) / 64, 256, 0, stream>>>(x, w1t, cnt, h1b, N);
    aggregate_l1<<<(N + 3) / 4, 256, 0, stream>>>((const unsigned int*)h1b, ell, cnt, b1, z1b, N);

    // layer 2 (A = bf16 z1)
    gemm_mfma<64, false><<<(N + 63) / 64, 256, 0, stream>>>(z1b, w2t, cnt, h2b, N);
    aggregate_l2<<<(N + 7) / 8, 256, 0, stream>>>((const unsigned int*)h2b, ell, cnt, b2, out, N);
}